// Round 11
// baseline (539.879 us; speedup 1.0000x reference)
//
#include <hip/hip_runtime.h>
#include <hip/hip_fp16.h>

// GAT 2-layer, N=100K, DIM=256, HID=16, NCLS=64, E=3.2M (+N self loops).
//  - CSR build: DIRECT via global atomics (replaces R8's 2-pass bucket
//    sort + p2 LDS fine-sort entirely): hist(deg) -> 2 tiny scans ->
//    scatter csr[atomicAdd(cursor[d])]=s. Atomics are SPREAD over 100K
//    L2-resident addresses (R6's disaster was same-address LDS x17/edge
//    -- different regime). csr order within a node is nondeterministic;
//    aggregation is an order-insensitive sum (fp tolerance OK).
//  - scatter role FUSED with h1 (role-interleaved blocks, R2-proven).
//  - h1 = x@W1 via MFMA f16 (16x16x32): 16-node tile/wave, 256-node
//    block grain, plain staged loads (R5/R8-proven 67us; R3 asm drains /
//    R4 sched_barrier / R7 DMA / R9 small-grain all regressed).
//  - agg core v2 (R8-proven): 16 lanes/node, 32-edge chunks, direct csr
//    indexing, double-buffered row gathers, RECOMPUTE-as (as[s]=h[s].a
//    8-FMA half-dot on the gathered row; no separate as[] gather).
//    32B node records keep the gather table L2-resident (3.2MB).
//  - R9/R10 lessons: 32-lane agg and p2+agg1 fusion both regress; v2
//    node-centric standalone is locally optimal.
//  - layer2 fused into agg2: as2/ad2 via vsd-dots; @W2+b2+log_softmax.

#define DIM 256
#define HID 16
#define NCLS 64
#define NEG 0.2f
#define P1_CHUNK 2048
#define KITER 8

typedef _Float16 f16x8 __attribute__((ext_vector_type(8)));
typedef float f32x4 __attribute__((ext_vector_type(4)));

__device__ __forceinline__ float lrelu(float v) { return v >= 0.f ? v : NEG * v; }

__device__ __forceinline__ uint4 pack_half8(const float* v) {
    __half2 p0 = __floats2half2_rn(v[0], v[1]);
    __half2 p1 = __floats2half2_rn(v[2], v[3]);
    __half2 p2 = __floats2half2_rn(v[4], v[5]);
    __half2 p3 = __floats2half2_rn(v[6], v[7]);
    return make_uint4(*(unsigned*)&p0, *(unsigned*)&p1, *(unsigned*)&p2, *(unsigned*)&p3);
}

__device__ __forceinline__ void unpack_half8(uint4 u, float* f) {
    float2 f0 = __half22float2(*(__half2*)&u.x);
    float2 f1 = __half22float2(*(__half2*)&u.y);
    float2 f2 = __half22float2(*(__half2*)&u.z);
    float2 f3 = __half22float2(*(__half2*)&u.w);
    f[0] = f0.x; f[1] = f0.y; f[2] = f1.x; f[3] = f1.y;
    f[4] = f2.x; f[5] = f2.y; f[6] = f3.x; f[7] = f3.y;
}

// vsd precompute + zero deg[] (grid-wide).
__global__ __launch_bounds__(1024) void vsd_zero_kernel(
    const float* __restrict__ W2, const float* __restrict__ as2,
    const float* __restrict__ ad2, float* __restrict__ vsd,
    int* __restrict__ deg, int n) {
    int i = blockIdx.x * 1024 + threadIdx.x;
    if (i < n) deg[i] = 0;
    if (blockIdx.x == 0 && threadIdx.x < 32) {
        int t = threadIdx.x;
        int j = t & 15;
        const float* a = (t < 16) ? as2 : ad2;
        float s = 0.f;
        for (int c = 0; c < NCLS; ++c) s += W2[j * NCLS + c] * a[c];
        vsd[t] = s;
    }
}

// Per-node degree histogram: one spread global atomic per edge.
__global__ __launch_bounds__(1024) void hist_kernel(const int* __restrict__ dst, int E,
                                                    int* __restrict__ deg) {
    int i4 = (blockIdx.x * 1024 + threadIdx.x) * 4;
    if (i4 + 3 < E) {
        int4 d4 = *(const int4*)&dst[i4];
        atomicAdd(&deg[d4.x], 1);
        atomicAdd(&deg[d4.y], 1);
        atomicAdd(&deg[d4.z], 1);
        atomicAdd(&deg[d4.w], 1);
    } else {
        for (int j = 0; j < 4; ++j)
            if (i4 + j < E) atomicAdd(&deg[dst[i4 + j]], 1);
    }
}

// scan1: block j scans deg[j*1024 .. +1024) -> within-block exclusive
// prefix in row_ptr; block total in btot[j].
__global__ __launch_bounds__(1024) void scan1_kernel(const int* __restrict__ deg,
                                                     int* __restrict__ row_ptr,
                                                     int* __restrict__ btot, int n) {
    __shared__ int arr[1024];
    int t = threadIdx.x;
    int i = blockIdx.x * 1024 + t;
    int v = (i < n) ? deg[i] : 0;
    arr[t] = v;
    __syncthreads();
    for (int o = 1; o < 1024; o <<= 1) {
        int x = (t >= o) ? arr[t - o] : 0;
        __syncthreads();
        arr[t] += x;
        __syncthreads();
    }
    if (i < n) row_ptr[i] = arr[t] - v;   // within-block exclusive
    if (t == 1023) btot[blockIdx.x] = arr[1023];
}

// finalize: every block redoes the tiny 128-scan of btot, then adds its
// base to row_ptr and seeds cursor.
__global__ __launch_bounds__(1024) void finalize_kernel(const int* __restrict__ btot,
                                                        int* __restrict__ row_ptr,
                                                        int* __restrict__ cursor,
                                                        int n, int nblk) {
    __shared__ int bs[128];
    int t = threadIdx.x;
    if (t < 128) bs[t] = (t < nblk) ? btot[t] : 0;
    __syncthreads();
    for (int o = 1; o < 128; o <<= 1) {
        int x = (t >= o && t < 128) ? bs[t - o] : 0;
        __syncthreads();
        if (t < 128) bs[t] += x;
        __syncthreads();
    }
    int base = (blockIdx.x == 0) ? 0 : bs[blockIdx.x - 1];
    int i = blockIdx.x * 1024 + t;
    if (i < n) {
        int rp = row_ptr[i] + base;
        row_ptr[i] = rp;
        cursor[i] = rp;
    }
}

// Fused direct-scatter + h1 MFMA, roles interleaved proportionally.
struct H1S {
    _Float16 w1t[16][264];    // W1^T f16, padded row stride (528B, 16B-mult)
    _Float16 hst[4][16][16];  // per-wave row staging for packed writeout
};

__global__ __launch_bounds__(256) void scat_h1_kernel(
    const int* __restrict__ ei, int E, int* __restrict__ cursor,
    int* __restrict__ csr, int nS, int h1blk,
    const float* __restrict__ x, const float* __restrict__ W1,
    uint4* __restrict__ h1h, int n) {
    __shared__ H1S sm;
    int t = threadIdx.x;
    int bid = blockIdx.x;
    int total = nS + h1blk;
    // proportional role interleave: block bid is an h1 block iff
    // floor((bid+1)*h1blk/total) > floor(bid*h1blk/total).
    int f0 = (int)(((long long)bid * h1blk) / total);
    int f1 = (int)(((long long)(bid + 1) * h1blk) / total);
    if (f1 == f0) {
        // ------------- direct scatter (no LDS, no staging) -------------
        int sb = bid - f0;
        int base = sb * P1_CHUNK;
        bool e4 = ((E & 3) == 0);
#pragma unroll
        for (int k = 0; k < KITER / 4; ++k) {
            int idx = base + (k * 256 + t) * 4;
            if (e4 && idx + 3 < E) {
                int4 s4 = *(const int4*)&ei[idx];
                int4 d4 = *(const int4*)&ei[E + idx];
                int p0 = atomicAdd(&cursor[d4.x], 1);
                int p1 = atomicAdd(&cursor[d4.y], 1);
                int p2 = atomicAdd(&cursor[d4.z], 1);
                int p3 = atomicAdd(&cursor[d4.w], 1);
                csr[p0] = s4.x;
                csr[p1] = s4.y;
                csr[p2] = s4.z;
                csr[p3] = s4.w;
            } else {
#pragma unroll
                for (int j = 0; j < 4; ++j) {
                    int id2 = idx + j;
                    if (id2 < E) {
                        int s = ei[id2], d = ei[E + id2];
                        csr[atomicAdd(&cursor[d], 1)] = s;
                    }
                }
            }
        }
    } else {
        // ---------------- h1 MFMA (R5/R8-proven form) ----------------
        int hb = f0;
        {
            const float* row = W1 + t * HID;  // t = k index 0..255
#pragma unroll
            for (int nn2 = 0; nn2 < 16; ++nn2)
                sm.w1t[nn2][t] = (_Float16)row[nn2];
        }
        __syncthreads();
        int lane = t & 63, wave = t >> 6;
        int q = lane >> 4, nn = lane & 15;
#pragma unroll 1
        for (int it = 0; it < 4; ++it) {
            int nb = hb * 256 + wave * 64 + it * 16;
            int node = nb + nn;
            const float* xr = x + (size_t)min(node, n - 1) * DIM;
            float4 st[16];
#pragma unroll
            for (int s = 0; s < 8; ++s) {
                int kb = s * 32 + q * 8;
                st[2 * s]     = *(const float4*)(xr + kb);
                st[2 * s + 1] = *(const float4*)(xr + kb + 4);
            }
            f32x4 acc = {0.f, 0.f, 0.f, 0.f};
#pragma unroll
            for (int s = 0; s < 8; ++s) {
                int kb = s * 32 + q * 8;
                f16x8 bf = *(const f16x8*)&sm.w1t[nn][kb];
                float4 a0 = st[2 * s], a1 = st[2 * s + 1];
                f16x8 af;
                af[0] = (_Float16)a0.x; af[1] = (_Float16)a0.y;
                af[2] = (_Float16)a0.z; af[3] = (_Float16)a0.w;
                af[4] = (_Float16)a1.x; af[5] = (_Float16)a1.y;
                af[6] = (_Float16)a1.z; af[7] = (_Float16)a1.w;
                acc = __builtin_amdgcn_mfma_f32_16x16x32_f16(af, bf, acc, 0, 0, 0);
            }
            if (nb < n) {  // wave-uniform
                // D[row=q*4+r][col=nn]; row = node-in-tile, col = j.
#pragma unroll
                for (int r = 0; r < 4; ++r)
                    sm.hst[wave][q * 4 + r][nn] = (_Float16)acc[r];
                __builtin_amdgcn_s_waitcnt(0);  // drain ds_writes (wave-lockstep)
                if (lane < 32) {
                    int nl = lane >> 1, jq = lane & 1;
                    int nd = nb + nl;
                    if (nd < n)
                        h1h[(size_t)nd * 2 + jq] = *(const uint4*)&sm.hst[wave][nl][jq * 8];
                }
            }
        }
    }
}

// ---- aggregation core v2 (R8-proven) --------------------------------------

// Node record: 32B = h f16x16 (stride 2 uint4). 16 lanes/node =
// (eq 0..7 edge-slot) x (jq 0..1 row-half); 32-edge chunks. Direct csr
// indexing (lane loads its own 4 indices), double-buffered gathers,
// RECOMPUTE-as. OOB lanes gather the node's own L1-hot row.
__device__ __forceinline__ void agg_core(
    const uint4* __restrict__ hh, const float* aw, const float* dw,
    int node, int start, int cnt, const int* __restrict__ csr,
    int eq, int jq, float* acc, float* hs, float& denomv) {
    unpack_half8(hh[(size_t)node * 2 + jq], hs);
    float asn = 0.f, adn = 0.f;
#pragma unroll
    for (int i = 0; i < 8; ++i) { asn += hs[i] * aw[i]; adn += hs[i] * dw[i]; }
    asn += __shfl_xor(asn, 1, 64);
    adn += __shfl_xor(adn, 1, 64);
    float adi = adn;
    float w0 = __expf(lrelu(asn + adi));
    float w0s = (eq == 0) ? w0 : 0.f;
#pragma unroll
    for (int i = 0; i < 8; ++i) acc[i] = w0s * hs[i];
    float denom = w0s;
    // prologue: indices + gathers for iteration 0
    int s0 = (eq < cnt)      ? csr[start + eq]      : node;
    int s1 = (8 + eq < cnt)  ? csr[start + 8 + eq]  : node;
    int s2 = (16 + eq < cnt) ? csr[start + 16 + eq] : node;
    int s3 = (24 + eq < cnt) ? csr[start + 24 + eq] : node;
    uint4 u0 = hh[(size_t)s0 * 2 + jq];
    uint4 u1 = hh[(size_t)s1 * 2 + jq];
    uint4 u2 = hh[(size_t)s2 * 2 + jq];
    uint4 u3 = hh[(size_t)s3 * 2 + jq];
#pragma unroll 1
    for (int q0 = 0; q0 < cnt; q0 += 32) {
        // next iteration's indices + gathers (in flight during compute)
        int nq = q0 + 32;
        int t0 = (nq + eq < cnt)      ? csr[start + nq + eq]      : node;
        int t1 = (nq + 8 + eq < cnt)  ? csr[start + nq + 8 + eq]  : node;
        int t2 = (nq + 16 + eq < cnt) ? csr[start + nq + 16 + eq] : node;
        int t3 = (nq + 24 + eq < cnt) ? csr[start + nq + 24 + eq] : node;
        uint4 v0 = hh[(size_t)t0 * 2 + jq];
        uint4 v1 = hh[(size_t)t1 * 2 + jq];
        uint4 v2 = hh[(size_t)t2 * 2 + jq];
        uint4 v3 = hh[(size_t)t3 * 2 + jq];
        // compute current 32 edges (4 slots of 8)
        float h[8], p, wv;
        unpack_half8(u0, h);
        p = 0.f;
#pragma unroll
        for (int i = 0; i < 8; ++i) p += h[i] * aw[i];
        p += __shfl_xor(p, 1, 64);
        wv = (q0 + eq < cnt) ? __expf(lrelu(p + adi)) : 0.f;
        denom += wv;
#pragma unroll
        for (int i = 0; i < 8; ++i) acc[i] += wv * h[i];
        unpack_half8(u1, h);
        p = 0.f;
#pragma unroll
        for (int i = 0; i < 8; ++i) p += h[i] * aw[i];
        p += __shfl_xor(p, 1, 64);
        wv = (q0 + 8 + eq < cnt) ? __expf(lrelu(p + adi)) : 0.f;
        denom += wv;
#pragma unroll
        for (int i = 0; i < 8; ++i) acc[i] += wv * h[i];
        unpack_half8(u2, h);
        p = 0.f;
#pragma unroll
        for (int i = 0; i < 8; ++i) p += h[i] * aw[i];
        p += __shfl_xor(p, 1, 64);
        wv = (q0 + 16 + eq < cnt) ? __expf(lrelu(p + adi)) : 0.f;
        denom += wv;
#pragma unroll
        for (int i = 0; i < 8; ++i) acc[i] += wv * h[i];
        unpack_half8(u3, h);
        p = 0.f;
#pragma unroll
        for (int i = 0; i < 8; ++i) p += h[i] * aw[i];
        p += __shfl_xor(p, 1, 64);
        wv = (q0 + 24 + eq < cnt) ? __expf(lrelu(p + adi)) : 0.f;
        denom += wv;
#pragma unroll
        for (int i = 0; i < 8; ++i) acc[i] += wv * h[i];
        u0 = v0; u1 = v1; u2 = v2; u3 = v3;
    }
#pragma unroll
    for (int m = 2; m <= 8; m <<= 1) {
#pragma unroll
        for (int i = 0; i < 8; ++i) acc[i] += __shfl_xor(acc[i], m, 64);
        denom += __shfl_xor(denom, m, 64);
    }
    denomv = denom;
}

__global__ __launch_bounds__(256) void agg1_kernel(
    const uint4* __restrict__ hh,
    const int* __restrict__ row_ptr, const int* __restrict__ deg, const int* __restrict__ csr,
    const float* __restrict__ as1, const float* __restrict__ ad1,
    const float* __restrict__ bias, uint4* __restrict__ outh, int n) {
    int t = threadIdx.x;
    int node = blockIdx.x * 16 + (t >> 4);
    if (node >= n) return;
    int lg = t & 15, jq = lg & 1, eq = lg >> 1;
    float aw[8], dw[8];
#pragma unroll
    for (int i = 0; i < 8; ++i) { aw[i] = as1[jq * 8 + i]; dw[i] = ad1[jq * 8 + i]; }
    float acc[8], hs[8];
    float denom;
    agg_core(hh, aw, dw, node, row_ptr[node], deg[node], csr, eq, jq, acc, hs, denom);
    float inv = 1.f / denom;
    float val[8];
#pragma unroll
    for (int i = 0; i < 8; ++i) val[i] = fmaxf(acc[i] * inv + bias[jq * 8 + i], 0.f);
    if (eq == 0) outh[(size_t)node * 2 + jq] = pack_half8(val);
}

__global__ __launch_bounds__(256) void agg2_final_kernel(
    const uint4* __restrict__ hh,
    const int* __restrict__ row_ptr, const int* __restrict__ deg, const int* __restrict__ csr,
    const float* __restrict__ vsd,
    const float* __restrict__ W2, const float* __restrict__ b2,
    float* __restrict__ out, int n) {
    __shared__ float a2s[16 * HID];
    __shared__ float w2s[HID * NCLS];
    __shared__ float b2s[NCLS];
    int t = threadIdx.x;
    for (int i = t; i < HID * NCLS; i += 256) w2s[i] = W2[i];
    if (t < NCLS) b2s[t] = b2[t];
    int g = t >> 4;
    int node = blockIdx.x * 16 + g;
    int lg = t & 15, jq = lg & 1, eq = lg >> 1;
    if (node < n) {
        float aw[8], dw[8];
#pragma unroll
        for (int i = 0; i < 8; ++i) { aw[i] = vsd[jq * 8 + i]; dw[i] = vsd[16 + jq * 8 + i]; }
        float acc[8], hs[8];
        float denom;
        agg_core(hh, aw, dw, node, row_ptr[node], deg[node], csr, eq, jq, acc, hs, denom);
        float inv = 1.f / denom;
        if (eq == 0) {
            float* dst = &a2s[g * HID + jq * 8];
            *(float4*)dst = make_float4(acc[0] * inv, acc[1] * inv, acc[2] * inv, acc[3] * inv);
            *(float4*)(dst + 4) = make_float4(acc[4] * inv, acc[5] * inv, acc[6] * inv, acc[7] * inv);
        }
    }
    __syncthreads();
    int wv = t >> 6;
    int c = t & 63;
#pragma unroll
    for (int i = 0; i < 4; ++i) {
        int nl = i * 4 + wv;
        int gn = blockIdx.x * 16 + nl;
        if (gn >= n) continue;
        const float* ar = &a2s[nl * HID];
        float v = b2s[c];
#pragma unroll
        for (int j = 0; j < HID; ++j) v += ar[j] * w2s[j * NCLS + c];
        float mx = v;
#pragma unroll
        for (int off = 1; off < 64; off <<= 1) mx = fmaxf(mx, __shfl_xor(mx, off, 64));
        float ex = __expf(v - mx);
        float s = ex;
#pragma unroll
        for (int off = 1; off < 64; off <<= 1) s += __shfl_xor(s, off, 64);
        out[(size_t)gn * NCLS + c] = (v - mx) - __logf(s);
    }
}

extern "C" void kernel_launch(void* const* d_in, const int* in_sizes, int n_in,
                              void* d_out, int out_size, void* d_ws, size_t ws_size,
                              hipStream_t stream) {
    const float* x    = (const float*)d_in[0];
    const int*   ei   = (const int*)d_in[1];  // [2,E]: [0..E)=src, [E..2E)=dst
    const float* W1   = (const float*)d_in[2];
    const float* a_s1 = (const float*)d_in[3];
    const float* a_d1 = (const float*)d_in[4];
    const float* b1   = (const float*)d_in[5];
    const float* W2   = (const float*)d_in[6];
    const float* a_s2 = (const float*)d_in[7];
    const float* a_d2 = (const float*)d_in[8];
    const float* b2   = (const float*)d_in[9];
    float* out = (float*)d_out;

    const int N = in_sizes[0] / DIM;
    const int E = in_sizes[1] / 2;
    const int nS = (E + P1_CHUNK - 1) / P1_CHUNK;
    const int h1blk = (N + 255) / 256;
    const int nscan = (N + 1023) / 1024;          // <= 128 enforced by design (N<=131072)
    const int nhist = (E / 4 + 1023) / 1024 + 1;

    char* p = (char*)d_ws;
    auto alloc = [&](size_t bytes) {
        char* r = p;
        p += (bytes + 255) & ~(size_t)255;
        return r;
    };
    int*   deg      = (int*)alloc((size_t)N * 4);
    int*   row_ptr  = (int*)alloc((size_t)N * 4);
    int*   cursor   = (int*)alloc((size_t)N * 4);
    int*   btot     = (int*)alloc(256 * 4);
    float* vsd      = (float*)alloc(32 * 4);
    int*   csr      = (int*)alloc((size_t)E * 4);
    uint4* h1h      = (uint4*)alloc((size_t)N * 32);   // 32B node records
    uint4* hreluh   = (uint4*)alloc((size_t)N * 32);

    vsd_zero_kernel<<<nscan, 1024, 0, stream>>>(W2, a_s2, a_d2, vsd, deg, N);
    hist_kernel<<<nhist, 1024, 0, stream>>>(ei + E, E, deg);
    scan1_kernel<<<nscan, 1024, 0, stream>>>(deg, row_ptr, btot, N);
    finalize_kernel<<<nscan, 1024, 0, stream>>>(btot, row_ptr, cursor, N, nscan);
    scat_h1_kernel<<<nS + h1blk, 256, 0, stream>>>(ei, E, cursor, csr, nS, h1blk,
                                                   x, W1, h1h, N);
    agg1_kernel<<<(N + 15) / 16, 256, 0, stream>>>(h1h, row_ptr, deg, csr,
                                                   a_s1, a_d1, b1, hreluh, N);
    agg2_final_kernel<<<(N + 15) / 16, 256, 0, stream>>>(hreluh, row_ptr, deg, csr,
                                                         vsd, W2, b2, out, N);
}